// Round 4
// baseline (119.398 us; speedup 1.0000x reference)
//
#include <hip/hip_runtime.h>

// XTermFrequency: per-row histogram + normalize.
//   assignments: [B=512, S=8192] int32 in [0, V=50257)
//   out:         [B, V] float32 = counts / S
//
// R4: single-pass, uint16-packed LDS histogram. Max count per row = S = 8192
// < 65536, so counts fit in 16 bits: full vocab = 50257 * 2 B = 100.5 KB LDS
// -> ONE block per row covers the whole vocab (no chunking, no row re-reads,
// only 2 barriers). 16-bit LDS atomics don't exist; emulate exactly with
// atomicAdd(&hist32[v>>1], 1 << ((v&1)*16)) -- low half can never carry into
// the high half since counts <= 8192. Row held in 8 VGPRs (2 x int4/thread,
// 1024 threads). Grid 512 = 2 rounds over 256 CUs (1 block/CU, LDS-limited).
// Output written exactly once, float4-vectorized (V odd => per-row rotating
// alignment, handled with head/tail fixup). scale = 1/8192 exact.

#define TF_BLOCK 1024
#define TF_WORDS 25129   // ceil(50257 / 2) packed uint16 pairs = 100.5 KB

__global__ __launch_bounds__(TF_BLOCK, 4)
void XTermFrequency_hist_kernel(const int* __restrict__ assign,
                                float* __restrict__ out,
                                int V, int S, float scale) {
    __shared__ unsigned int hist[TF_WORDS];
    const int row = blockIdx.x;
    const int tid = threadIdx.x;

    // Kick off the row load (VMEM) ...
    const int4* __restrict__ rowp = (const int4*)(assign + (size_t)row * S);
    const int4 va = rowp[tid];
    const int4 vb = rowp[tid + TF_BLOCK];

    // ... while zeroing the packed histogram (LDS pipe).
    for (int i = tid; i < TF_WORDS; i += TF_BLOCK) hist[i] = 0u;
    __syncthreads();

    // Scatter: one exact 16-bit-packed atomic per value (8 per thread).
    {
        unsigned int u;
        u = (unsigned int)va.x; atomicAdd(&hist[u >> 1], 1u << ((u & 1u) << 4));
        u = (unsigned int)va.y; atomicAdd(&hist[u >> 1], 1u << ((u & 1u) << 4));
        u = (unsigned int)va.z; atomicAdd(&hist[u >> 1], 1u << ((u & 1u) << 4));
        u = (unsigned int)va.w; atomicAdd(&hist[u >> 1], 1u << ((u & 1u) << 4));
        u = (unsigned int)vb.x; atomicAdd(&hist[u >> 1], 1u << ((u & 1u) << 4));
        u = (unsigned int)vb.y; atomicAdd(&hist[u >> 1], 1u << ((u & 1u) << 4));
        u = (unsigned int)vb.z; atomicAdd(&hist[u >> 1], 1u << ((u & 1u) << 4));
        u = (unsigned int)vb.w; atomicAdd(&hist[u >> 1], 1u << ((u & 1u) << 4));
    }
    __syncthreads();

    // Write-out: unpack uint16 counts, normalize, float4-coalesced stores.
    float* dst = out + (size_t)row * V;
    auto cnt = [&](int i) -> float {
        return (float)((hist[i >> 1] >> ((i & 1) << 4)) & 0xFFFFu) * scale;
    };

    int head = (int)((4u - (((unsigned int)(size_t)dst >> 2) & 3u)) & 3u);
    if (head > V) head = V;
    if (tid < head) dst[tid] = cnt(tid);

    const int n4 = (V - head) >> 2;
    float4* __restrict__ dst4 = (float4*)(dst + head);
    for (int j = tid; j < n4; j += TF_BLOCK) {
        const int i = head + 4 * j;
        float4 o;
        o.x = cnt(i);
        o.y = cnt(i + 1);
        o.z = cnt(i + 2);
        o.w = cnt(i + 3);
        dst4[j] = o;
    }

    const int done = head + 4 * n4;
    const int rem = V - done;
    if (tid < rem) dst[done + tid] = cnt(done + tid);
}

extern "C" void kernel_launch(void* const* d_in, const int* in_sizes, int n_in,
                              void* d_out, int out_size, void* d_ws, size_t ws_size,
                              hipStream_t stream) {
    const int* assign = (const int*)d_in[0];
    float* out = (float*)d_out;

    const int V = 50257;
    const int B = out_size / V;          // 512
    const int S = in_sizes[0] / B;       // 8192
    const float scale = 1.0f / (float)S; // exact power of two

    XTermFrequency_hist_kernel<<<dim3(B), dim3(TF_BLOCK), 0, stream>>>(
        assign, out, V, S, scale);
}

// Round 5
// 117.958 us; speedup vs baseline: 1.0122x; 1.0122x over previous
//
#include <hip/hip_runtime.h>

// XTermFrequency: per-row histogram + normalize.
//   assignments: [B=512, S=8192] int32 in [0, V=50257)
//   out:         [B, V] float32 = counts / S
//
// R5: uint16-packed LDS histogram (counts <= 8192 fit in 16 bits; packed
// atomicAdd(&w[v>>1], 1<<((v&1)*16)) is exact -- low half can't carry),
// split each row across 2 blocks, each owning half the vocab:
//   half word range = 12565 packed words = 50.3 KB LDS -> 3 blocks/CU,
//   grid 512x2 = 1024 blocks x 512 threads = 24 waves/CU.
// Each block re-reads its full row (2x read amp = 32 MB total, ~L2/HBM
// trivial), scatters only in-range values, 2 barriers, writes its half of
// the output exactly once (float4, head/tail fixup for V odd).
// This maximizes block-level overlap of zero/scatter/write phases vs R4's
// 1 block/CU 2-round structure -- discriminates "phase serialization" vs
// "fixed harness overhead" as the residual bottleneck.

#define TF_BLOCK 512
#define TF_HWORDS 12565   // packed words per half: covers 2*12565=25130 bins

__global__ __launch_bounds__(TF_BLOCK, 6)
void XTermFrequency_hist_kernel(const int* __restrict__ assign,
                                float* __restrict__ out,
                                int V, int S, float scale) {
    __shared__ unsigned int hist[TF_HWORDS];
    const int row = blockIdx.x;
    const int half = blockIdx.y;
    const int wbase = half * TF_HWORDS;            // first packed word owned
    const int bin0 = wbase * 2;                    // first bin owned
    const int nbins = min(V - bin0, TF_HWORDS * 2);
    const int tid = threadIdx.x;

    // Kick off row load (4 int4/thread) while zeroing LDS.
    const int4* __restrict__ rowp = (const int4*)(assign + (size_t)row * S);
    int4 v0 = rowp[tid];
    int4 v1 = rowp[tid + TF_BLOCK];
    int4 v2 = rowp[tid + 2 * TF_BLOCK];
    int4 v3 = rowp[tid + 3 * TF_BLOCK];

    for (int i = tid; i < TF_HWORDS; i += TF_BLOCK) hist[i] = 0u;
    __syncthreads();

    // Scatter in-range values (packed 16-bit halves, exact).
    auto scat = [&](int x) {
        const unsigned int u = (unsigned int)x;
        const unsigned int d = (u >> 1) - (unsigned int)wbase;
        if (d < (unsigned int)TF_HWORDS)
            atomicAdd(&hist[d], 1u << ((u & 1u) << 4));
    };
    scat(v0.x); scat(v0.y); scat(v0.z); scat(v0.w);
    scat(v1.x); scat(v1.y); scat(v1.z); scat(v1.w);
    scat(v2.x); scat(v2.y); scat(v2.z); scat(v2.w);
    scat(v3.x); scat(v3.y); scat(v3.z); scat(v3.w);
    __syncthreads();

    // Write-out this block's half: unpack, normalize, float4 stores.
    float* dst = out + (size_t)row * V + bin0;
    auto cnt = [&](int i) -> float {   // i = local bin index within half
        return (float)((hist[i >> 1] >> ((i & 1) << 4)) & 0xFFFFu) * scale;
    };

    int head = (int)((4u - (((unsigned int)(size_t)dst >> 2) & 3u)) & 3u);
    if (head > nbins) head = nbins;
    if (tid < head) dst[tid] = cnt(tid);

    const int n4 = (nbins - head) >> 2;
    float4* __restrict__ dst4 = (float4*)(dst + head);
    for (int j = tid; j < n4; j += TF_BLOCK) {
        const int i = head + 4 * j;
        float4 o;
        o.x = cnt(i);
        o.y = cnt(i + 1);
        o.z = cnt(i + 2);
        o.w = cnt(i + 3);
        dst4[j] = o;
    }

    const int done = head + 4 * n4;
    const int rem = nbins - done;
    if (tid < rem) dst[done + tid] = cnt(done + tid);
}

extern "C" void kernel_launch(void* const* d_in, const int* in_sizes, int n_in,
                              void* d_out, int out_size, void* d_ws, size_t ws_size,
                              hipStream_t stream) {
    const int* assign = (const int*)d_in[0];
    float* out = (float*)d_out;

    const int V = 50257;
    const int B = out_size / V;          // 512
    const int S = in_sizes[0] / B;       // 8192
    const float scale = 1.0f / (float)S; // exact power of two

    XTermFrequency_hist_kernel<<<dim3(B, 2), dim3(TF_BLOCK), 0, stream>>>(
        assign, out, V, S, scale);
}